// Round 11
// baseline (261.903 us; speedup 1.0000x reference)
//
#include <hip/hip_runtime.h>
#include <hip/hip_bf16.h>

#define B_  2
#define T_  2048
#define D_  1024
#define H_  16
#define KH_ 4
#define DH_ 64

typedef __attribute__((ext_vector_type(8))) short bf16x8;   // 8 bf16 = 4 VGPRs
typedef __attribute__((ext_vector_type(4))) float f32x4;
typedef __attribute__((ext_vector_type(16))) float f32x16;  // 32x32 MFMA acc

// log2(e)/8: folded into Q at projection time so softmax is p = exp2(s_raw).
#define QSCALE 0.18033688011112043f

#if defined(__has_builtin)
#  if __has_builtin(__builtin_amdgcn_exp2f)
#    define EXP2F(x) __builtin_amdgcn_exp2f(x)
#  endif
#endif
#ifndef EXP2F
#  define EXP2F(x) exp2f(x)
#endif

// fp32 -> bf16 RNE (scalar, for prep paths where cvt_pk doesn't fit)
__device__ __forceinline__ unsigned short f2bf(float f) {
  union { float f; unsigned int u; } v; v.f = f;
  return (unsigned short)((v.u + 0x7FFFu + ((v.u >> 16) & 1u)) >> 16);
}
// packed fp32x2 -> bf16x2 via v_cvt_pk_bf16_f32 (1 VALU op)
__device__ __forceinline__ unsigned int pk2(float a, float b) {
  union { __hip_bfloat162 h2; unsigned int u; } v;
  v.h2 = __float22bfloat162_rn(make_float2(a, b));
  return v.u;
}

// async global->LDS, 16B per lane. LDS dest = wave-uniform base + lane*16;
// global source is per-lane (pre-swizzled source pattern, m173/rule #21).
__device__ __forceinline__ void g2l16(const void* g, void* l) {
  __builtin_amdgcn_global_load_lds(
      (const __attribute__((address_space(1))) void*)g,
      (__attribute__((address_space(3))) void*)l, 16, 0, 0);
}

// Permutations (all ours, all per-head bijections — exact):
//  sigma_qk (Q/K d-storage, UNCHANGED): slot(d) = (d&15)*4 + (d>>4).
//    QK contraction is invariant to any shared Q/K permutation.
//  sigma_att (att d-storage + WoT k-rows, NEW): slot(d) = (d&31)*2 + (d>>5).
//    Lets the 32x32 attn epilogue emit coalesced b32 stores (d and d+32
//    adjacent). Outproj contraction invariant (WoT prepped to match).
//  V key-position map (NEW, for 32x32 in-register P): position p (0..63)
//    holds key tok(p) with bits k0<-p0,k1<-p1,k2<-p3,k3<-p2,k4<-p4,k5<-p5
//    (bit2<->bit3 swap) — built so each lane's PV A-operand is exactly its
//    own reg-sequential exp'd QK outputs (correct for any shared operand
//    k-order by kappa-symmetry of A/B layouts).

// ---------------------------------------------------------------------------
// Merged prep (one launch). Only change vs r9: WoT k-row permutation is
// sigma_att(kr) = (kr&31)*2 + (kr>>5) to match the new attn store order.
// ---------------------------------------------------------------------------
__global__ __launch_bounds__(256) void prep_kernel(
    const float* __restrict__ x,  const float* __restrict__ Wq,
    const float* __restrict__ Wk, const float* __restrict__ Wv,
    const float* __restrict__ Wo,
    short* __restrict__ xb, short* __restrict__ WT, short* __restrict__ WoT,
    float2* __restrict__ tbl) {
  __shared__ short Ts[64 * 72];
  const int bid = blockIdx.x, tid = threadIdx.x;

  if (bid < 2048) {                             // ---- x -> bf16
    const size_t i8 = ((size_t)bid * 256 + tid) * 8;
    const float4 a = *(const float4*)&x[i8];
    const float4 b = *(const float4*)&x[i8 + 4];
    uint4 p; p.x = pk2(a.x, a.y); p.y = pk2(a.z, a.w);
    p.z = pk2(b.x, b.y); p.w = pk2(b.z, b.w);
    *(uint4*)&xb[i8] = p;
  } else if (bid < 2688) {                      // ---- WT / WoT transpose
    const bool isW = bid < 2432;
    const int idx = isW ? (bid - 2048) : (bid - 2432);
    const int n0 = (idx >> 4) * 64, k0 = (idx & 15) * 64;
    const float* src; int ncols, c0; short* dst;
    if (isW) {
      dst = WT;
      if (n0 < 1024)      { src = Wq; ncols = 1024; c0 = n0; }
      else if (n0 < 1280) { src = Wk; ncols = 256;  c0 = n0 - 1024; }
      else                { src = Wv; ncols = 256;  c0 = n0 - 1280; }
    } else { dst = WoT; src = Wo; ncols = 1024; c0 = n0; }
    for (int i = tid; i < 1024; i += 256) {
      const int kr = i >> 4, c4 = (i & 15) << 2;
      // WoT k-rows permuted by sigma_att (k0 is 64-aligned = one head).
      const int kc = isW ? kr : ((kr & 31) * 2 + (kr >> 5));
      const float4 w = *(const float4*)&src[(size_t)(k0 + kr) * ncols + c0 + c4];
      Ts[(c4 + 0) * 72 + kc] = (short)f2bf(w.x);
      Ts[(c4 + 1) * 72 + kc] = (short)f2bf(w.y);
      Ts[(c4 + 2) * 72 + kc] = (short)f2bf(w.z);
      Ts[(c4 + 3) * 72 + kc] = (short)f2bf(w.w);
    }
    __syncthreads();
    for (int c = tid; c < 512; c += 256) {
      const int nr = c >> 3, c8 = (c & 7) * 8;
      *(bf16x8*)&dst[(size_t)(n0 + nr) * 1024 + k0 + c8] =
          *(const bf16x8*)&Ts[nr * 72 + c8];
    }
  } else {                                      // ---- RoPE table
    const int e = (bid - 2688) * 256 + tid;     // 65536 entries
    const int t = e >> 5, i2 = e & 31;
    const float freq = exp2f(-(float)(2 * i2) * (18.931568569324174f / 64.0f));
    float sn, cs; sincosf((float)t * freq, &sn, &cs);
    tbl[e] = make_float2(cs, sn);
  }
}

// ---------------------------------------------------------------------------
// Kernel 1: QKV projection [r6/r9 structure]: 128x64 tiles, 2-phase BK=64
// double-buffered counted-vmcnt loop, XCD-chunked grid 768. Only change:
// V-transpose epilogue uses the NEW key-position map (bit2<->bit3 swap).
// ---------------------------------------------------------------------------
__global__ __launch_bounds__(256) void qkv_mfma_kernel(
    const short* __restrict__ xb, const short* __restrict__ WT,
    const float2* __restrict__ tbl,
    short* __restrict__ qo, short* __restrict__ ko, short* __restrict__ vt) {
  __shared__ short Xsh[2][128 * 64];
  __shared__ short Wth[2][64 * 64];
  const int tid = threadIdx.x;
  const int lane = tid & 63, w = tid >> 6;
  const int lm = lane & 15, quad = lane >> 4;
  const int bid = blockIdx.x;
  const int xcd = bid & 7, slot = bid >> 3;     // slot 0..95
  const int m0 = (xcd * 4 + (slot & 3)) * 128;  // 0..3968
  const int n0 = (slot >> 2) * 64;              // 0..1472

  f32x4 acc[2][4];
  #pragma unroll
  for (int sm = 0; sm < 2; ++sm)
    #pragma unroll
    for (int ct = 0; ct < 4; ++ct) acc[sm][ct] = (f32x4){0.f, 0.f, 0.f, 0.f};

  auto stage = [&](int kt, int bsel) {
    #pragma unroll
    for (int u = 0; u < 4; ++u) {               // Xs: 128 rows
      const int r = u * 32 + w * 8 + (lane >> 3);
      const int sb = (lane & 7) ^ (r & 7);
      g2l16(&xb[(size_t)(m0 + r) * 1024 + kt * 64 + sb * 8],
            &Xsh[bsel][(u * 32 + w * 8) * 64]);
    }
    #pragma unroll
    for (int u = 0; u < 2; ++u) {               // Wt: 64 rows
      const int r = u * 32 + w * 8 + (lane >> 3);
      const int sb = (lane & 7) ^ (r & 7);
      g2l16(&WT[(size_t)(n0 + r) * 1024 + kt * 64 + sb * 8],
            &Wth[bsel][(u * 32 + w * 8) * 64]);
    }
  };

  stage(0, 0);
  for (int kt = 0; kt < 16; ++kt) {
    const int bsel = kt & 1;
    if (kt < 15) {
      stage(kt + 1, bsel ^ 1);
      asm volatile("s_waitcnt vmcnt(6)" ::: "memory");
    } else {
      asm volatile("s_waitcnt vmcnt(0)" ::: "memory");
    }
    __builtin_amdgcn_s_barrier();
    __builtin_amdgcn_sched_barrier(0);
    #pragma unroll
    for (int s2 = 0; s2 < 2; ++s2) {
      bf16x8 bfr[4];
      #pragma unroll
      for (int ct = 0; ct < 4; ++ct)
        bfr[ct] = *(const bf16x8*)&Wth[bsel][(ct * 16 + lm) * 64 +
                                            (((s2 * 4 + quad) ^ (lm & 7)) << 3)];
      #pragma unroll
      for (int sm = 0; sm < 2; ++sm) {
        const bf16x8 a = *(const bf16x8*)&Xsh[bsel][(w * 32 + sm * 16 + lm) * 64 +
                                            (((s2 * 4 + quad) ^ (lm & 7)) << 3)];
        #pragma unroll
        for (int ct = 0; ct < 4; ++ct)
          acc[sm][ct] =
              __builtin_amdgcn_mfma_f32_16x16x32_bf16(a, bfr[ct], acc[sm][ct], 0, 0, 0);
      }
    }
    __builtin_amdgcn_sched_barrier(0);
    __builtin_amdgcn_s_barrier();
  }

  if (n0 < 1280) {                              // ---- Q or K: RoPE + b64 store
    const bool isQ = n0 < 1024;
    short* outp = isQ ? qo : ko;
    const int base = isQ ? n0 : n0 - 1024;
    const int nh = isQ ? H_ : KH_;
    const int hh = base >> 6;
    const float post = isQ ? QSCALE : 1.0f;
    #pragma unroll
    for (int sm = 0; sm < 2; ++sm)
      #pragma unroll
      for (int r = 0; r < 4; ++r) {
        const int row = m0 + w * 32 + sm * 16 + quad * 4 + r;
        const int b = row >> 11, t = row & 2047;
        float v4[4];
        #pragma unroll
        for (int ct = 0; ct < 4; ++ct) {
          float val = acc[sm][ct][r];
          const float other = __shfl_xor(val, 1);
          const int ci = ct * 16 + lm;
          const float2 cs = tbl[t * 32 + (ci >> 1)];
          val = ((ci & 1) == 0) ? (val * cs.x - other * cs.y)
                                : (val * cs.x + other * cs.y);
          v4[ct] = val * post;
        }
        // d ct*16+lm -> sigma_qk slot lm*4+ct: one b64 store
        uint2 st; st.x = pk2(v4[0], v4[1]); st.y = pk2(v4[2], v4[3]);
        *(uint2*)&outp[((size_t)(b * nh + hh) * T_ + t) * DH_ + lm * 4] = st;
      }
  } else {                                      // ---- V: LDS-bounce transpose
    short* XsF = &Xsh[0][0];
    __syncthreads();
    #pragma unroll
    for (int sm = 0; sm < 2; ++sm)
      #pragma unroll
      for (int r = 0; r < 4; ++r)
        #pragma unroll
        for (int ct = 0; ct < 4; ++ct)
          XsF[(w * 32 + sm * 16 + quad * 4 + r) * 72 + ct * 16 + lm] =
              (short)f2bf(acc[sm][ct][r]);
    __syncthreads();
    const int kh = (n0 - 1280) >> 6;
    const int b = m0 >> 11, t0 = m0 & 2047;
    short* vb = vt + (size_t)(b * KH_ + kh) * DH_ * T_;
    for (int c = tid; c < 1024; c += 256) {
      const int d = c >> 4, c8 = (c & 15) * 8;
      short tmp[8];
      #pragma unroll
      for (int j = 0; j < 8; ++j) {
        const int s = c8 + j, p = s & 63;       // position -> token (new map)
        // k0<-p0,k1<-p1,k2<-p3,k3<-p2,k4<-p4,k5<-p5 (bit2<->bit3 swap)
        const int tok = (s & 64) | (p & 51) | (((p >> 3) & 1) << 2) |
                        (((p >> 2) & 1) << 3);
        tmp[j] = XsF[tok * 72 + d];
      }
      *(bf16x8*)&vb[(size_t)d * T_ + t0 + c8] = *(bf16x8*)tmp;
    }
  }
}

// ---------------------------------------------------------------------------
// Kernel 2: causal flash attention, 32x32-MFMA swapped-QK in-register-P.
// 4 waves = (wq q-half) x (wk key-half) of each 64q x 64key step: one
// fragment read feeds 32 q-rows (vs 16) -> per-CU LDS window 2280->1140 cyc
// (the measured bottleneck), MFMA 0.296->0.246 cyc/kFLOP. Grid 1024 = 4/CU,
// constant-66-step balance, (256,4) with live state trimmed to ~115 VGPR
// (scalar rowsum instead of ones-MFMA; pairwise exp->pk2; pd = 8 u32) —
// preserves ALL invariants the failed restructures broke. wk contraction
// split healed once at epilogue via LDS (Ks/Vts region reused); coalesced
// b32 stores in sigma_att order. Ks stride 66 / Vts stride 130:
// conflict-free 32-row reads. s_setprio around MFMA clusters (T5).
// ---------------------------------------------------------------------------
__global__ __launch_bounds__(256, 4) void attn_mfma_kernel(
    const short* __restrict__ q, const short* __restrict__ k,
    const short* __restrict__ vt, short* __restrict__ att) {
  __shared__ __align__(16) short SMEM[16768];   // Ks[128*66] | Vts[64*130]
  short* Ks = SMEM;                             // 8448 shorts
  short* Vts = SMEM + 8448;                     // 8320 shorts

  const int bx = blockIdx.x;
  const int jj = bx & 255, c2 = bx >> 8;
  int qt = (c2 & 1) ? (jj >> 3) : (31 - (jj >> 3));   // heavy-first in chunk 0
  const int hb = (jj & 7) | (c2 << 3);
  const int h = hb >> 1, b = hb & 1;
  const int kh = h >> 2;                        // n_rep = 4
  const int tid = threadIdx.x;
  const int lane = tid & 63, w = tid >> 6;
  const int wq = w >> 1, wk = w & 1;            // q-half x key-half
  const int l5 = lane & 31, hi = lane >> 5;
  const int q0 = qt * 64;

  const short* qb = q + (size_t)(b * H_ + h) * T_ * DH_;
  const short* kb = k + (size_t)(b * KH_ + kh) * T_ * DH_;
  const short* vb = vt + (size_t)(b * KH_ + kh) * DH_ * T_;

  // Q B-frags (sigma_qk positions, shared with K -> contraction invariant)
  bf16x8 aq0, aq1, aq2, aq3;
  {
    const short* qr = &qb[(size_t)(q0 + wq * 32 + l5) * 64 + hi * 8];
    aq0 = *(const bf16x8*)&qr[0];
    aq1 = *(const bf16x8*)&qr[16];
    aq2 = *(const bf16x8*)&qr[32];
    aq3 = *(const bf16x8*)&qr[48];
  }

  bf16x8 pk[4], pv[4];
  #pragma unroll
  for (int u = 0; u < 4; ++u) {                 // preload r2=0 (128 keys)
    const int c = tid + u * 256;
    const int row = c >> 3, c8 = (c & 7) * 8;
    pk[u] = *(const bf16x8*)&kb[(size_t)row * 64 + c8];
    const int d = c >> 4, c16 = (c & 15) * 8;
    pv[u] = *(const bf16x8*)&vb[(size_t)d * T_ + c16];
  }

  f32x16 oacc0, oacc1;                          // d-tiles 0..31 / 32..63
  #pragma unroll
  for (int i = 0; i < 16; ++i) { oacc0[i] = 0.f; oacc1[i] = 0.f; }
  float lsum = 0.f;

  // one 64-key tile-step; this wave covers q wq*32.. x keys j*64+wk*32..
  auto step = [&](int j, bool diag) {
    const bool skipall = diag && (wk > wq);     // quadrant above diagonal
    const bool dg = diag && (wk == wq);         // diagonal 32x32 quadrant
    f32x16 sacc;
    #pragma unroll
    for (int i = 0; i < 16; ++i) sacc[i] = 0.f;
    if (!skipall) {
      const short* kbase = &Ks[(j * 64 + wk * 32 + l5) * 66 + hi * 8];
      __builtin_amdgcn_s_setprio(1);
      sacc = __builtin_amdgcn_mfma_f32_32x32x16_bf16(*(const bf16x8*)&kbase[0],  aq0, sacc, 0, 0, 0);
      sacc = __builtin_amdgcn_mfma_f32_32x32x16_bf16(*(const bf16x8*)&kbase[16], aq1, sacc, 0, 0, 0);
      sacc = __builtin_amdgcn_mfma_f32_32x32x16_bf16(*(const bf16x8*)&kbase[32], aq2, sacc, 0, 0, 0);
      sacc = __builtin_amdgcn_mfma_f32_32x32x16_bf16(*(const bf16x8*)&kbase[48], aq3, sacc, 0, 0, 0);
      __builtin_amdgcn_s_setprio(0);
    }
    // in-lane softmax: sacc[r] = P[key (r&3)+8*(r>>2)+4*hi][q = l5]
    unsigned int pd[8];
    #pragma unroll
    for (int i = 0; i < 8; ++i) {
      float e0 = 0.f, e1 = 0.f;
      if (!skipall) {
        const int r0 = 2 * i;
        e0 = EXP2F(sacc[r0]);
        e1 = EXP2F(sacc[r0 + 1]);
        if (dg) {
          const int k0 = (r0 & 3) + 8 * (r0 >> 2) + 4 * hi;
          if (k0 > l5) e0 = 0.f;
          if (k0 + 1 > l5) e1 = 0.f;            // causal mask
        }
      }
      lsum += e0 + e1;
      pd[i] = pk2(e0, e1);
    }
    if (!skipall) {
      const short* vbase = &Vts[l5 * 130 + j * 64 + wk * 32 + hi * 8];
      __builtin_amdgcn_s_setprio(1);
      union { bf16x8 v; unsigned int u[4]; } pa;
      pa.u[0] = pd[0]; pa.u[1] = pd[1]; pa.u[2] = pd[2]; pa.u[3] = pd[3];
      oacc0 = __builtin_amdgcn_mfma_f32_32x32x16_bf16(pa.v, *(const bf16x8*)&vbase[0],        oacc0, 0, 0, 0);
      oacc1 = __builtin_amdgcn_mfma_f32_32x32x16_bf16(pa.v, *(const bf16x8*)&vbase[32 * 130], oacc1, 0, 0, 0);
      pa.u[0] = pd[4]; pa.u[1] = pd[5]; pa.u[2] = pd[6]; pa.u[3] = pd[7];
      oacc0 = __builtin_amdgcn_mfma_f32_32x32x16_bf16(pa.v, *(const bf16x8*)&vbase[16],            oacc0, 0, 0, 0);
      oacc1 = __builtin_amdgcn_mfma_f32_32x32x16_bf16(pa.v, *(const bf16x8*)&vbase[32 * 130 + 16], oacc1, 0, 0, 0);
      __builtin_amdgcn_s_setprio(0);
    }
  };

  auto stage = [&](int r2) {
    __syncthreads();                            // prior K/V LDS reads done
    #pragma unroll
    for (int u = 0; u < 4; ++u) {
      const int c = tid + u * 256;
      const int row = c >> 3, c8 = (c & 7) * 8;
      *(bf16x8*)&Ks[row * 66 + c8] = pk[u];
      const int d = c >> 4, c16 = (c & 15) * 8;
      *(bf16x8*)&Vts[d * 130 + c16] = pv[u];
    }
    __syncthreads();
    const int r2n = (r2 + 2 <= qt) ? (r2 + 2) : r2;   // prefetch next pair
    #pragma unroll
    for (int u = 0; u < 4; ++u) {
      const int c = tid + u * 256;
      const int row = c >> 3, c8 = (c & 7) * 8;
      pk[u] = *(const bf16x8*)&kb[(size_t)(r2n * 64 + row) * 64 + c8];
      const int d = c >> 4, c16 = (c & 15) * 8;
      pv[u] = *(const bf16x8*)&vb[(size_t)d * T_ + r2n * 64 + c16];
    }
  };

  int r2 = 0;
  for (; r2 + 1 <= qt; r2 += 2) {               // full pairs only
    stage(r2);
    step(0, false);                             // never diagonal
    step(1, r2 + 1 == qt);                      // diagonal only on last pair
  }
  if (r2 == qt) {                               // peeled final step (even qt)
    stage(r2);
    step(0, true);
  }

  // ---- cross-wk reduction through reused LDS + coalesced sigma_att store
  lsum += __shfl_xor(lsum, 32);                 // full 32-key-half rowsum
  __syncthreads();                              // all K/V LDS reads done
  float* RED = (float*)SMEM;                    // [2*64 lanes][36] (pad 4)
  float* LSQ = RED + 2 * 64 * 36;               // [2 wk][64 q]
  LSQ[wk * 64 + wq * 32 + l5] = lsum;           // dup write benign
  const int base = (wq * 64 + lane) * 36;
  if (wk == 1) {
    #pragma unroll
    for (int i = 0; i < 4; ++i) {
      f32x4 t0 = {oacc0[4*i], oacc0[4*i+1], oacc0[4*i+2], oacc0[4*i+3]};
      *(f32x4*)&RED[base + i * 4] = t0;
      f32x4 t1 = {oacc1[4*i], oacc1[4*i+1], oacc1[4*i+2], oacc1[4*i+3]};
      *(f32x4*)&RED[base + 16 + i * 4] = t1;
    }
  }
  __syncthreads();
  if (wk == 0) {
    #pragma unroll
    for (int i = 0; i < 4; ++i) {
      const f32x4 t0 = *(const f32x4*)&RED[base + i * 4];
      const f32x4 t1 = *(const f32x4*)&RED[base + 16 + i * 4];
      #pragma unroll
      for (int jx = 0; jx < 4; ++jx) {
        oacc0[4*i + jx] += t0[jx];
        oacc1[4*i + jx] += t1[jx];
      }
    }
    #pragma unroll
    for (int r = 0; r < 16; ++r) {
      const int qr = (r & 3) + 8 * (r >> 2) + 4 * hi;   // q within 32-block
      const float inv = 1.f / (LSQ[wq * 32 + qr] + LSQ[64 + wq * 32 + qr]);
      const unsigned int pw = pk2(oacc0[r] * inv, oacc1[r] * inv);
      // sigma_att: d=l5 -> slot 2*l5, d=32+l5 -> slot 2*l5+1 (adjacent)
      *(unsigned int*)&att[((size_t)b * T_ + q0 + wq * 32 + qr) * 1024 +
                           h * 64 + l5 * 2] = pw;
    }
  }
}

// ---------------------------------------------------------------------------
// Kernel 3: output projection [r6/r9 exact code]: 128x64 tiles, 2-phase
// BK=64 counted-vmcnt loop, XCD-chunked grid 512. (att k-dim and WoT k-rows
// both in sigma_att order — contraction invariant.)
// ---------------------------------------------------------------------------
__global__ __launch_bounds__(256) void outproj_mfma_kernel(
    const short* __restrict__ att, const short* __restrict__ WoT,
    float* __restrict__ out) {
  __shared__ short Xsh[2][128 * 64];
  __shared__ short Wth[2][64 * 64];
  const int tid = threadIdx.x;
  const int lane = tid & 63, w = tid >> 6;
  const int lm = lane & 15, quad = lane >> 4;
  const int bid = blockIdx.x;
  const int xcd = bid & 7, slot = bid >> 3;     // slot 0..63
  const int m0 = (xcd * 4 + (slot & 3)) * 128;
  const int n0 = (slot >> 2) * 64;              // 0..960

  f32x4 acc[2][4];
  #pragma unroll
  for (int sm = 0; sm < 2; ++sm)
    #pragma unroll
    for (int ct = 0; ct < 4; ++ct) acc[sm][ct] = (f32x4){0.f, 0.f, 0.f, 0.f};

  auto stage = [&](int kt, int bsel) {
    #pragma unroll
    for (int u = 0; u < 4; ++u) {
      const int r = u * 32 + w * 8 + (lane >> 3);
      const int sb = (lane & 7) ^ (r & 7);
      g2l16(&att[(size_t)(m0 + r) * 1024 + kt * 64 + sb * 8],
            &Xsh[bsel][(u * 32 + w * 8) * 64]);
    }
    #pragma unroll
    for (int u = 0; u < 2; ++u) {
      const int r = u * 32 + w * 8 + (lane >> 3);
      const int sb = (lane & 7) ^ (r & 7);
      g2l16(&WoT[(size_t)(n0 + r) * 1024 + kt * 64 + sb * 8],
            &Wth[bsel][(u * 32 + w * 8) * 64]);
    }
  };

  stage(0, 0);
  for (int kt = 0; kt < 16; ++kt) {
    const int bsel = kt & 1;
    if (kt < 15) {
      stage(kt + 1, bsel ^ 1);
      asm volatile("s_waitcnt vmcnt(6)" ::: "memory");
    } else {
      asm volatile("s_waitcnt vmcnt(0)" ::: "memory");
    }
    __builtin_amdgcn_s_barrier();
    __builtin_amdgcn_sched_barrier(0);
    #pragma unroll
    for (int s2 = 0; s2 < 2; ++s2) {
      bf16x8 bfr[4];
      #pragma unroll
      for (int ct = 0; ct < 4; ++ct)
        bfr[ct] = *(const bf16x8*)&Wth[bsel][(ct * 16 + lm) * 64 +
                                            (((s2 * 4 + quad) ^ (lm & 7)) << 3)];
      #pragma unroll
      for (int sm = 0; sm < 2; ++sm) {
        const bf16x8 a = *(const bf16x8*)&Xsh[bsel][(w * 32 + sm * 16 + lm) * 64 +
                                            (((s2 * 4 + quad) ^ (lm & 7)) << 3)];
        #pragma unroll
        for (int ct = 0; ct < 4; ++ct)
          acc[sm][ct] =
              __builtin_amdgcn_mfma_f32_16x16x32_bf16(a, bfr[ct], acc[sm][ct], 0, 0, 0);
      }
    }
    __builtin_amdgcn_sched_barrier(0);
    __builtin_amdgcn_s_barrier();
  }

  #pragma unroll
  for (int sm = 0; sm < 2; ++sm)
    #pragma unroll
    for (int r = 0; r < 4; ++r) {
      const int row = m0 + w * 32 + sm * 16 + quad * 4 + r;
      #pragma unroll
      for (int ct = 0; ct < 4; ++ct)
        out[(size_t)row * 1024 + n0 + ct * 16 + lm] = acc[sm][ct][r];
    }
}

extern "C" void kernel_launch(void* const* d_in, const int* in_sizes, int n_in,
                              void* d_out, int out_size, void* d_ws, size_t ws_size,
                              hipStream_t stream) {
  const float* x  = (const float*)d_in[0];
  // d_in[1] = mask: fixed causal tril, handled analytically; never read.
  const float* Wq = (const float*)d_in[2];
  const float* Wk = (const float*)d_in[3];
  const float* Wv = (const float*)d_in[4];
  const float* Wo = (const float*)d_in[5];
  float* out = (float*)d_out;

  short* xb   = (short*)d_ws;
  short* WT   = xb  + (size_t)4194304;          // 1536*1024
  short* WoT  = WT  + (size_t)1572864;          // 1024*1024 (k sigma_att order)
  short* qb   = WoT + (size_t)1048576;          // 2*16*2048*64 (sigma_qk slots)
  short* kb   = qb  + (size_t)4194304;          // 2*4*2048*64 (sigma_qk slots)
  short* vtb  = kb  + (size_t)1048576;          // 2*4*64*2048 (new key-pos map)
  short* attb = vtb + (size_t)1048576;          // 2*2048*1024 (sigma_att order)
  float2* tbl = (float2*)(attb + (size_t)4194304);  // 2048*32 float2

  prep_kernel<<<dim3(2944), dim3(256), 0, stream>>>(
      x, Wq, Wk, Wv, Wo, xb, WT, WoT, tbl);
  qkv_mfma_kernel<<<dim3(768), dim3(256), 0, stream>>>(xb, WT, tbl, qb, kb, vtb);
  attn_mfma_kernel<<<dim3(1024), dim3(256), 0, stream>>>(qb, kb, vtb, attb);
  outproj_mfma_kernel<<<dim3(512), dim3(256), 0, stream>>>(attb, WoT, out);
}

// Round 12
// 192.098 us; speedup vs baseline: 1.3634x; 1.3634x over previous
//
#include <hip/hip_runtime.h>
#include <hip/hip_bf16.h>

#define B_  2
#define T_  2048
#define D_  1024
#define H_  16
#define KH_ 4
#define DH_ 64

typedef __attribute__((ext_vector_type(8))) short bf16x8;   // 8 bf16 = 4 VGPRs
typedef __attribute__((ext_vector_type(4))) float f32x4;
typedef __attribute__((ext_vector_type(16))) float f32x16;  // 32x32 MFMA acc

// log2(e)/8: folded into Q at projection time so softmax is p = exp2(s_raw).
#define QSCALE 0.18033688011112043f

#if defined(__has_builtin)
#  if __has_builtin(__builtin_amdgcn_exp2f)
#    define EXP2F(x) __builtin_amdgcn_exp2f(x)
#  endif
#endif
#ifndef EXP2F
#  define EXP2F(x) exp2f(x)
#endif

// fp32 -> bf16 RNE (scalar, for prep paths where cvt_pk doesn't fit)
__device__ __forceinline__ unsigned short f2bf(float f) {
  union { float f; unsigned int u; } v; v.f = f;
  return (unsigned short)((v.u + 0x7FFFu + ((v.u >> 16) & 1u)) >> 16);
}
// packed fp32x2 -> bf16x2 via v_cvt_pk_bf16_f32 (1 VALU op)
__device__ __forceinline__ unsigned int pk2(float a, float b) {
  union { __hip_bfloat162 h2; unsigned int u; } v;
  v.h2 = __float22bfloat162_rn(make_float2(a, b));
  return v.u;
}

// async global->LDS, 16B per lane. LDS dest = wave-uniform base + lane*16;
// global source is per-lane (pre-swizzled source pattern, m173/rule #21).
__device__ __forceinline__ void g2l16(const void* g, void* l) {
  __builtin_amdgcn_global_load_lds(
      (const __attribute__((address_space(1))) void*)g,
      (__attribute__((address_space(3))) void*)l, 16, 0, 0);
}

// Permutations (all ours, all per-head bijections — exact, r11-verified):
//  sigma_qk (Q/K d-storage): slot(d) = (d&15)*4 + (d>>4).
//  sigma_att (att d-storage + WoT k-rows): slot(d) = (d&31)*2 + (d>>5).
//  V key-position map (32x32 in-register P): position p holds key tok(p),
//    bits k0<-p0,k1<-p1,k2<-p3,k3<-p2,k4<-p4,k5<-p5 (bit2<->bit3 swap).

// ---------------------------------------------------------------------------
// Merged prep (one launch). [byte-identical to r11]
// ---------------------------------------------------------------------------
__global__ __launch_bounds__(256) void prep_kernel(
    const float* __restrict__ x,  const float* __restrict__ Wq,
    const float* __restrict__ Wk, const float* __restrict__ Wv,
    const float* __restrict__ Wo,
    short* __restrict__ xb, short* __restrict__ WT, short* __restrict__ WoT,
    float2* __restrict__ tbl) {
  __shared__ short Ts[64 * 72];
  const int bid = blockIdx.x, tid = threadIdx.x;

  if (bid < 2048) {                             // ---- x -> bf16
    const size_t i8 = ((size_t)bid * 256 + tid) * 8;
    const float4 a = *(const float4*)&x[i8];
    const float4 b = *(const float4*)&x[i8 + 4];
    uint4 p; p.x = pk2(a.x, a.y); p.y = pk2(a.z, a.w);
    p.z = pk2(b.x, b.y); p.w = pk2(b.z, b.w);
    *(uint4*)&xb[i8] = p;
  } else if (bid < 2688) {                      // ---- WT / WoT transpose
    const bool isW = bid < 2432;
    const int idx = isW ? (bid - 2048) : (bid - 2432);
    const int n0 = (idx >> 4) * 64, k0 = (idx & 15) * 64;
    const float* src; int ncols, c0; short* dst;
    if (isW) {
      dst = WT;
      if (n0 < 1024)      { src = Wq; ncols = 1024; c0 = n0; }
      else if (n0 < 1280) { src = Wk; ncols = 256;  c0 = n0 - 1024; }
      else                { src = Wv; ncols = 256;  c0 = n0 - 1280; }
    } else { dst = WoT; src = Wo; ncols = 1024; c0 = n0; }
    for (int i = tid; i < 1024; i += 256) {
      const int kr = i >> 4, c4 = (i & 15) << 2;
      // WoT k-rows permuted by sigma_att (k0 is 64-aligned = one head).
      const int kc = isW ? kr : ((kr & 31) * 2 + (kr >> 5));
      const float4 w = *(const float4*)&src[(size_t)(k0 + kr) * ncols + c0 + c4];
      Ts[(c4 + 0) * 72 + kc] = (short)f2bf(w.x);
      Ts[(c4 + 1) * 72 + kc] = (short)f2bf(w.y);
      Ts[(c4 + 2) * 72 + kc] = (short)f2bf(w.z);
      Ts[(c4 + 3) * 72 + kc] = (short)f2bf(w.w);
    }
    __syncthreads();
    for (int c = tid; c < 512; c += 256) {
      const int nr = c >> 3, c8 = (c & 7) * 8;
      *(bf16x8*)&dst[(size_t)(n0 + nr) * 1024 + k0 + c8] =
          *(const bf16x8*)&Ts[nr * 72 + c8];
    }
  } else {                                      // ---- RoPE table
    const int e = (bid - 2688) * 256 + tid;     // 65536 entries
    const int t = e >> 5, i2 = e & 31;
    const float freq = exp2f(-(float)(2 * i2) * (18.931568569324174f / 64.0f));
    float sn, cs; sincosf((float)t * freq, &sn, &cs);
    tbl[e] = make_float2(cs, sn);
  }
}

// ---------------------------------------------------------------------------
// Kernel 1: QKV projection [byte-identical to r11]: 128x64 tiles, 2-phase
// BK=64 counted-vmcnt loop, XCD-chunked grid 768; V-transpose epilogue
// writes the bit2<->bit3 key-position map.
// ---------------------------------------------------------------------------
__global__ __launch_bounds__(256) void qkv_mfma_kernel(
    const short* __restrict__ xb, const short* __restrict__ WT,
    const float2* __restrict__ tbl,
    short* __restrict__ qo, short* __restrict__ ko, short* __restrict__ vt) {
  __shared__ short Xsh[2][128 * 64];
  __shared__ short Wth[2][64 * 64];
  const int tid = threadIdx.x;
  const int lane = tid & 63, w = tid >> 6;
  const int lm = lane & 15, quad = lane >> 4;
  const int bid = blockIdx.x;
  const int xcd = bid & 7, slot = bid >> 3;     // slot 0..95
  const int m0 = (xcd * 4 + (slot & 3)) * 128;  // 0..3968
  const int n0 = (slot >> 2) * 64;              // 0..1472

  f32x4 acc[2][4];
  #pragma unroll
  for (int sm = 0; sm < 2; ++sm)
    #pragma unroll
    for (int ct = 0; ct < 4; ++ct) acc[sm][ct] = (f32x4){0.f, 0.f, 0.f, 0.f};

  auto stage = [&](int kt, int bsel) {
    #pragma unroll
    for (int u = 0; u < 4; ++u) {               // Xs: 128 rows
      const int r = u * 32 + w * 8 + (lane >> 3);
      const int sb = (lane & 7) ^ (r & 7);
      g2l16(&xb[(size_t)(m0 + r) * 1024 + kt * 64 + sb * 8],
            &Xsh[bsel][(u * 32 + w * 8) * 64]);
    }
    #pragma unroll
    for (int u = 0; u < 2; ++u) {               // Wt: 64 rows
      const int r = u * 32 + w * 8 + (lane >> 3);
      const int sb = (lane & 7) ^ (r & 7);
      g2l16(&WT[(size_t)(n0 + r) * 1024 + kt * 64 + sb * 8],
            &Wth[bsel][(u * 32 + w * 8) * 64]);
    }
  };

  stage(0, 0);
  for (int kt = 0; kt < 16; ++kt) {
    const int bsel = kt & 1;
    if (kt < 15) {
      stage(kt + 1, bsel ^ 1);
      asm volatile("s_waitcnt vmcnt(6)" ::: "memory");
    } else {
      asm volatile("s_waitcnt vmcnt(0)" ::: "memory");
    }
    __builtin_amdgcn_s_barrier();
    __builtin_amdgcn_sched_barrier(0);
    #pragma unroll
    for (int s2 = 0; s2 < 2; ++s2) {
      bf16x8 bfr[4];
      #pragma unroll
      for (int ct = 0; ct < 4; ++ct)
        bfr[ct] = *(const bf16x8*)&Wth[bsel][(ct * 16 + lm) * 64 +
                                            (((s2 * 4 + quad) ^ (lm & 7)) << 3)];
      #pragma unroll
      for (int sm = 0; sm < 2; ++sm) {
        const bf16x8 a = *(const bf16x8*)&Xsh[bsel][(w * 32 + sm * 16 + lm) * 64 +
                                            (((s2 * 4 + quad) ^ (lm & 7)) << 3)];
        #pragma unroll
        for (int ct = 0; ct < 4; ++ct)
          acc[sm][ct] =
              __builtin_amdgcn_mfma_f32_16x16x32_bf16(a, bfr[ct], acc[sm][ct], 0, 0, 0);
      }
    }
    __builtin_amdgcn_sched_barrier(0);
    __builtin_amdgcn_s_barrier();
  }

  if (n0 < 1280) {                              // ---- Q or K: RoPE + b64 store
    const bool isQ = n0 < 1024;
    short* outp = isQ ? qo : ko;
    const int base = isQ ? n0 : n0 - 1024;
    const int nh = isQ ? H_ : KH_;
    const int hh = base >> 6;
    const float post = isQ ? QSCALE : 1.0f;
    #pragma unroll
    for (int sm = 0; sm < 2; ++sm)
      #pragma unroll
      for (int r = 0; r < 4; ++r) {
        const int row = m0 + w * 32 + sm * 16 + quad * 4 + r;
        const int b = row >> 11, t = row & 2047;
        float v4[4];
        #pragma unroll
        for (int ct = 0; ct < 4; ++ct) {
          float val = acc[sm][ct][r];
          const float other = __shfl_xor(val, 1);
          const int ci = ct * 16 + lm;
          const float2 cs = tbl[t * 32 + (ci >> 1)];
          val = ((ci & 1) == 0) ? (val * cs.x - other * cs.y)
                                : (val * cs.x + other * cs.y);
          v4[ct] = val * post;
        }
        // d ct*16+lm -> sigma_qk slot lm*4+ct: one b64 store
        uint2 st; st.x = pk2(v4[0], v4[1]); st.y = pk2(v4[2], v4[3]);
        *(uint2*)&outp[((size_t)(b * nh + hh) * T_ + t) * DH_ + lm * 4] = st;
      }
  } else {                                      // ---- V: LDS-bounce transpose
    short* XsF = &Xsh[0][0];
    __syncthreads();
    #pragma unroll
    for (int sm = 0; sm < 2; ++sm)
      #pragma unroll
      for (int r = 0; r < 4; ++r)
        #pragma unroll
        for (int ct = 0; ct < 4; ++ct)
          XsF[(w * 32 + sm * 16 + quad * 4 + r) * 72 + ct * 16 + lm] =
              (short)f2bf(acc[sm][ct][r]);
    __syncthreads();
    const int kh = (n0 - 1280) >> 6;
    const int b = m0 >> 11, t0 = m0 & 2047;
    short* vb = vt + (size_t)(b * KH_ + kh) * DH_ * T_;
    for (int c = tid; c < 1024; c += 256) {
      const int d = c >> 4, c8 = (c & 15) * 8;
      short tmp[8];
      #pragma unroll
      for (int j = 0; j < 8; ++j) {
        const int s = c8 + j, p = s & 63;       // position -> token
        // k0<-p0,k1<-p1,k2<-p3,k3<-p2,k4<-p4,k5<-p5 (bit2<->bit3 swap)
        const int tok = (s & 64) | (p & 51) | (((p >> 3) & 1) << 2) |
                        (((p >> 2) & 1) << 3);
        tmp[j] = XsF[tok * 72 + d];
      }
      *(bf16x8*)&vb[(size_t)d * T_ + t0 + c8] = *(bf16x8*)tmp;
    }
  }
}

// ---------------------------------------------------------------------------
// Kernel 2: causal flash attention, 32x32-MFMA swapped-QK in-register-P
// [r11 math, correctness HW-verified] with the spill fixed: r11's 145MB
// WRITE_SIZE was arch-VGPR overflow under the 64/64 arch/acc partition of
// (256,4)'s 128-reg cap (arch side aq16+pk16+pv16+pd8+addr ~= 75 > 64).
// Fix: V is now staged via g2l16 into LINEAR Vts[64][128] with rule-#21
// source-side XOR (pos = (B&8)|((B&7)^(row&7)), same involution on read —
// cancels exactly, so the verified key-position map is unchanged), freeing
// pv's 16 arch regs -> arch ~= 56 <= 64, no spill. V visibility comes free
// from __syncthreads()'s vmcnt(0) drain; pk keeps reg prefetch (HBM latency
// hiding). Everything else identical to r11.
// ---------------------------------------------------------------------------
__global__ __launch_bounds__(256, 4) void attn_mfma_kernel(
    const short* __restrict__ q, const short* __restrict__ k,
    const short* __restrict__ vt, short* __restrict__ att) {
  __shared__ __align__(16) short SMEM[16640];   // Ks[128*66] | Vts[64*128]
  short* Ks = SMEM;                             // 8448 shorts
  short* Vts = SMEM + 8448;                     // 8192 shorts, linear

  const int bx = blockIdx.x;
  const int jj = bx & 255, c2 = bx >> 8;
  int qt = (c2 & 1) ? (jj >> 3) : (31 - (jj >> 3));   // heavy-first in chunk 0
  const int hb = (jj & 7) | (c2 << 3);
  const int h = hb >> 1, b = hb & 1;
  const int kh = h >> 2;                        // n_rep = 4
  const int tid = threadIdx.x;
  const int lane = tid & 63, w = tid >> 6;
  const int wq = w >> 1, wk = w & 1;            // q-half x key-half
  const int l5 = lane & 31, hi = lane >> 5;
  const int q0 = qt * 64;

  const short* qb = q + (size_t)(b * H_ + h) * T_ * DH_;
  const short* kb = k + (size_t)(b * KH_ + kh) * T_ * DH_;
  const short* vb = vt + (size_t)(b * KH_ + kh) * DH_ * T_;

  // Q B-frags (sigma_qk positions, shared with K -> contraction invariant)
  bf16x8 aq0, aq1, aq2, aq3;
  {
    const short* qr = &qb[(size_t)(q0 + wq * 32 + l5) * 64 + hi * 8];
    aq0 = *(const bf16x8*)&qr[0];
    aq1 = *(const bf16x8*)&qr[16];
    aq2 = *(const bf16x8*)&qr[32];
    aq3 = *(const bf16x8*)&qr[48];
  }

  bf16x8 pk[4];
  #pragma unroll
  for (int u = 0; u < 4; ++u) {                 // preload r2=0 K (128 keys)
    const int c = tid + u * 256;
    const int row = c >> 3, c8 = (c & 7) * 8;
    pk[u] = *(const bf16x8*)&kb[(size_t)row * 64 + c8];
  }

  f32x16 oacc0, oacc1;                          // d-tiles 0..31 / 32..63
  #pragma unroll
  for (int i = 0; i < 16; ++i) { oacc0[i] = 0.f; oacc1[i] = 0.f; }
  float lsum = 0.f;

  // one 64-key tile-step; this wave covers q wq*32.. x keys j*64+wk*32..
  auto step = [&](int j, bool diag) {
    const bool skipall = diag && (wk > wq);     // quadrant above diagonal
    const bool dg = diag && (wk == wq);         // diagonal 32x32 quadrant
    f32x16 sacc;
    #pragma unroll
    for (int i = 0; i < 16; ++i) sacc[i] = 0.f;
    if (!skipall) {
      const short* kbase = &Ks[(j * 64 + wk * 32 + l5) * 66 + hi * 8];
      __builtin_amdgcn_s_setprio(1);
      sacc = __builtin_amdgcn_mfma_f32_32x32x16_bf16(*(const bf16x8*)&kbase[0],  aq0, sacc, 0, 0, 0);
      sacc = __builtin_amdgcn_mfma_f32_32x32x16_bf16(*(const bf16x8*)&kbase[16], aq1, sacc, 0, 0, 0);
      sacc = __builtin_amdgcn_mfma_f32_32x32x16_bf16(*(const bf16x8*)&kbase[32], aq2, sacc, 0, 0, 0);
      sacc = __builtin_amdgcn_mfma_f32_32x32x16_bf16(*(const bf16x8*)&kbase[48], aq3, sacc, 0, 0, 0);
      __builtin_amdgcn_s_setprio(0);
    }
    // in-lane softmax: sacc[r] = P[key (r&3)+8*(r>>2)+4*hi][q = l5]
    unsigned int pd[8];
    #pragma unroll
    for (int i = 0; i < 8; ++i) {
      float e0 = 0.f, e1 = 0.f;
      if (!skipall) {
        const int r0 = 2 * i;
        e0 = EXP2F(sacc[r0]);
        e1 = EXP2F(sacc[r0 + 1]);
        if (dg) {
          const int k0 = (r0 & 3) + 8 * (r0 >> 2) + 4 * hi;
          if (k0 > l5) e0 = 0.f;
          if (k0 + 1 > l5) e1 = 0.f;            // causal mask
        }
      }
      lsum += e0 + e1;
      pd[i] = pk2(e0, e1);
    }
    if (!skipall) {
      // V reads: logical block B = j*8 + wk*4 + hi (+2 for second frag);
      // stored at position (B&8)|((B&7)^(row&7)) — XOR cancels staging swz.
      const int B0 = j * 8 + wk * 4 + hi;
      const int p0 = (B0 & 8) | ((B0 & 7) ^ (l5 & 7));
      const int p2 = ((B0 + 2) & 8) | (((B0 + 2) & 7) ^ (l5 & 7));
      __builtin_amdgcn_s_setprio(1);
      union { bf16x8 v; unsigned int u[4]; } pa;
      pa.u[0] = pd[0]; pa.u[1] = pd[1]; pa.u[2] = pd[2]; pa.u[3] = pd[3];
      oacc0 = __builtin_amdgcn_mfma_f32_32x32x16_bf16(pa.v, *(const bf16x8*)&Vts[l5 * 128 + p0 * 8],        oacc0, 0, 0, 0);
      oacc1 = __builtin_amdgcn_mfma_f32_32x32x16_bf16(pa.v, *(const bf16x8*)&Vts[(32 + l5) * 128 + p0 * 8], oacc1, 0, 0, 0);
      pa.u[0] = pd[4]; pa.u[1] = pd[5]; pa.u[2] = pd[6]; pa.u[3] = pd[7];
      oacc0 = __builtin_amdgcn_mfma_f32_32x32x16_bf16(pa.v, *(const bf16x8*)&Vts[l5 * 128 + p2 * 8],        oacc0, 0, 0, 0);
      oacc1 = __builtin_amdgcn_mfma_f32_32x32x16_bf16(pa.v, *(const bf16x8*)&Vts[(32 + l5) * 128 + p2 * 8], oacc1, 0, 0, 0);
      __builtin_amdgcn_s_setprio(0);
    }
  };

  auto stage = [&](int r2) {
    __syncthreads();                            // prior K/V LDS reads done
    #pragma unroll
    for (int u = 0; u < 4; ++u) {               // K: reg -> LDS (stride 66)
      const int c = tid + u * 256;
      const int row = c >> 3, c8 = (c & 7) * 8;
      *(bf16x8*)&Ks[row * 66 + c8] = pk[u];
    }
    #pragma unroll
    for (int u = 0; u < 4; ++u) {               // V: g2l16, source-XOR swz
      const int c = tid + u * 256;              // c 0..1023
      const int row = c >> 4, pos = c & 15;     // d-row, 16B position
      const int blk = (pos & 8) | ((pos & 7) ^ (row & 7));
      g2l16(&vb[(size_t)row * T_ + r2 * 64 + blk * 8],
            &Vts[(u * 256 + w * 64) * 8]);      // linear dest, lane*16B
    }
    __syncthreads();                            // drains vmcnt(0): V landed
    const int r2n = (r2 + 2 <= qt) ? (r2 + 2) : r2;   // prefetch next K pair
    #pragma unroll
    for (int u = 0; u < 4; ++u) {
      const int c = tid + u * 256;
      const int row = c >> 3, c8 = (c & 7) * 8;
      pk[u] = *(const bf16x8*)&kb[(size_t)(r2n * 64 + row) * 64 + c8];
    }
  };

  int r2 = 0;
  for (; r2 + 1 <= qt; r2 += 2) {               // full pairs only
    stage(r2);
    step(0, false);                             // never diagonal
    step(1, r2 + 1 == qt);                      // diagonal only on last pair
  }
  if (r2 == qt) {                               // peeled final step (even qt)
    stage(r2);
    step(0, true);
  }

  // ---- cross-wk reduction through reused LDS + coalesced sigma_att store
  lsum += __shfl_xor(lsum, 32);                 // full 32-key-half rowsum
  __syncthreads();                              // all K/V LDS reads done
  float* RED = (float*)SMEM;                    // [2*64 lanes][36] (pad 4)
  float* LSQ = RED + 2 * 64 * 36;               // [2 wk][64 q]
  LSQ[wk * 64 + wq * 32 + l5] = lsum;           // dup write benign
  const int base = (wq * 64 + lane) * 36;
  if (wk == 1) {
    #pragma unroll
    for (int i = 0; i < 4; ++i) {
      f32x4 t0 = {oacc0[4*i], oacc0[4*i+1], oacc0[4*i+2], oacc0[4*i+3]};
      *(f32x4*)&RED[base + i * 4] = t0;
      f32x4 t1 = {oacc1[4*i], oacc1[4*i+1], oacc1[4*i+2], oacc1[4*i+3]};
      *(f32x4*)&RED[base + 16 + i * 4] = t1;
    }
  }
  __syncthreads();
  if (wk == 0) {
    #pragma unroll
    for (int i = 0; i < 4; ++i) {
      const f32x4 t0 = *(const f32x4*)&RED[base + i * 4];
      const f32x4 t1 = *(const f32x4*)&RED[base + 16 + i * 4];
      #pragma unroll
      for (int jx = 0; jx < 4; ++jx) {
        oacc0[4*i + jx] += t0[jx];
        oacc1[4*i + jx] += t1[jx];
      }
    }
    #pragma unroll
    for (int r = 0; r < 16; ++r) {
      const int qr = (r & 3) + 8 * (r >> 2) + 4 * hi;   // q within 32-block
      const float inv = 1.f / (LSQ[wq * 32 + qr] + LSQ[64 + wq * 32 + qr]);
      const unsigned int pw = pk2(oacc0[r] * inv, oacc1[r] * inv);
      // sigma_att: d=l5 -> slot 2*l5, d=32+l5 -> slot 2*l5+1 (adjacent)
      *(unsigned int*)&att[((size_t)b * T_ + q0 + wq * 32 + qr) * 1024 +
                           h * 64 + l5 * 2] = pw;
    }
  }
}

// ---------------------------------------------------------------------------
// Kernel 3: output projection [byte-identical to r11]: 128x64 tiles,
// 2-phase BK=64 counted-vmcnt loop, XCD-chunked grid 512.
// ---------------------------------------------------------------------------
__global__ __launch_bounds__(256) void outproj_mfma_kernel(
    const short* __restrict__ att, const short* __restrict__ WoT,
    float* __restrict__ out) {
  __shared__ short Xsh[2][128 * 64];
  __shared__ short Wth[2][64 * 64];
  const int tid = threadIdx.x;
  const int lane = tid & 63, w = tid >> 6;
  const int lm = lane & 15, quad = lane >> 4;
  const int bid = blockIdx.x;
  const int xcd = bid & 7, slot = bid >> 3;     // slot 0..63
  const int m0 = (xcd * 4 + (slot & 3)) * 128;
  const int n0 = (slot >> 2) * 64;              // 0..960

  f32x4 acc[2][4];
  #pragma unroll
  for (int sm = 0; sm < 2; ++sm)
    #pragma unroll
    for (int ct = 0; ct < 4; ++ct) acc[sm][ct] = (f32x4){0.f, 0.f, 0.f, 0.f};

  auto stage = [&](int kt, int bsel) {
    #pragma unroll
    for (int u = 0; u < 4; ++u) {
      const int r = u * 32 + w * 8 + (lane >> 3);
      const int sb = (lane & 7) ^ (r & 7);
      g2l16(&att[(size_t)(m0 + r) * 1024 + kt * 64 + sb * 8],
            &Xsh[bsel][(u * 32 + w * 8) * 64]);
    }
    #pragma unroll
    for (int u = 0; u < 2; ++u) {
      const int r = u * 32 + w * 8 + (lane >> 3);
      const int sb = (lane & 7) ^ (r & 7);
      g2l16(&WoT[(size_t)(n0 + r) * 1024 + kt * 64 + sb * 8],
            &Wth[bsel][(u * 32 + w * 8) * 64]);
    }
  };

  stage(0, 0);
  for (int kt = 0; kt < 16; ++kt) {
    const int bsel = kt & 1;
    if (kt < 15) {
      stage(kt + 1, bsel ^ 1);
      asm volatile("s_waitcnt vmcnt(6)" ::: "memory");
    } else {
      asm volatile("s_waitcnt vmcnt(0)" ::: "memory");
    }
    __builtin_amdgcn_s_barrier();
    __builtin_amdgcn_sched_barrier(0);
    #pragma unroll
    for (int s2 = 0; s2 < 2; ++s2) {
      bf16x8 bfr[4];
      #pragma unroll
      for (int ct = 0; ct < 4; ++ct)
        bfr[ct] = *(const bf16x8*)&Wth[bsel][(ct * 16 + lm) * 64 +
                                            (((s2 * 4 + quad) ^ (lm & 7)) << 3)];
      #pragma unroll
      for (int sm = 0; sm < 2; ++sm) {
        const bf16x8 a = *(const bf16x8*)&Xsh[bsel][(w * 32 + sm * 16 + lm) * 64 +
                                            (((s2 * 4 + quad) ^ (lm & 7)) << 3)];
        #pragma unroll
        for (int ct = 0; ct < 4; ++ct)
          acc[sm][ct] =
              __builtin_amdgcn_mfma_f32_16x16x32_bf16(a, bfr[ct], acc[sm][ct], 0, 0, 0);
      }
    }
    __builtin_amdgcn_sched_barrier(0);
    __builtin_amdgcn_s_barrier();
  }

  #pragma unroll
  for (int sm = 0; sm < 2; ++sm)
    #pragma unroll
    for (int r = 0; r < 4; ++r) {
      const int row = m0 + w * 32 + sm * 16 + quad * 4 + r;
      #pragma unroll
      for (int ct = 0; ct < 4; ++ct)
        out[(size_t)row * 1024 + n0 + ct * 16 + lm] = acc[sm][ct][r];
    }
}

extern "C" void kernel_launch(void* const* d_in, const int* in_sizes, int n_in,
                              void* d_out, int out_size, void* d_ws, size_t ws_size,
                              hipStream_t stream) {
  const float* x  = (const float*)d_in[0];
  // d_in[1] = mask: fixed causal tril, handled analytically; never read.
  const float* Wq = (const float*)d_in[2];
  const float* Wk = (const float*)d_in[3];
  const float* Wv = (const float*)d_in[4];
  const float* Wo = (const float*)d_in[5];
  float* out = (float*)d_out;

  short* xb   = (short*)d_ws;
  short* WT   = xb  + (size_t)4194304;          // 1536*1024
  short* WoT  = WT  + (size_t)1572864;          // 1024*1024 (k sigma_att order)
  short* qb   = WoT + (size_t)1048576;          // 2*16*2048*64 (sigma_qk slots)
  short* kb   = qb  + (size_t)4194304;          // 2*4*2048*64 (sigma_qk slots)
  short* vtb  = kb  + (size_t)1048576;          // 2*4*64*2048 (key-pos map)
  short* attb = vtb + (size_t)1048576;          // 2*2048*1024 (sigma_att order)
  float2* tbl = (float2*)(attb + (size_t)4194304);  // 2048*32 float2

  prep_kernel<<<dim3(2944), dim3(256), 0, stream>>>(
      x, Wq, Wk, Wv, Wo, xb, WT, WoT, tbl);
  qkv_mfma_kernel<<<dim3(768), dim3(256), 0, stream>>>(xb, WT, tbl, qb, kb, vtb);
  attn_mfma_kernel<<<dim3(1024), dim3(256), 0, stream>>>(qb, kb, vtb, attb);
  outproj_mfma_kernel<<<dim3(512), dim3(256), 0, stream>>>(attb, WoT, out);
}

// Round 13
// 169.184 us; speedup vs baseline: 1.5480x; 1.1354x over previous
//
#include <hip/hip_runtime.h>
#include <hip/hip_bf16.h>

#define B_  2
#define T_  2048
#define D_  1024
#define H_  16
#define KH_ 4
#define DH_ 64

typedef __attribute__((ext_vector_type(8))) short bf16x8;   // 8 bf16 = 4 VGPRs
typedef __attribute__((ext_vector_type(4))) float f32x4;

// log2(e)/8: folded into Q at projection time so softmax is p = exp2(s_raw).
#define QSCALE 0.18033688011112043f

// single-instruction v_exp_f32 if available (OCML exp2f is ~10 instrs)
#if defined(__has_builtin)
#  if __has_builtin(__builtin_amdgcn_exp2f)
#    define EXP2F(x) __builtin_amdgcn_exp2f(x)
#  endif
#endif
#ifndef EXP2F
#  define EXP2F(x) exp2f(x)
#endif

// fp32 -> bf16 RNE (scalar, for prep paths where cvt_pk doesn't fit)
__device__ __forceinline__ unsigned short f2bf(float f) {
  union { float f; unsigned int u; } v; v.f = f;
  return (unsigned short)((v.u + 0x7FFFu + ((v.u >> 16) & 1u)) >> 16);
}
// packed fp32x2 -> bf16x2 via v_cvt_pk_bf16_f32 (1 VALU op)
__device__ __forceinline__ unsigned int pk2(float a, float b) {
  union { __hip_bfloat162 h2; unsigned int u; } v;
  v.h2 = __float22bfloat162_rn(make_float2(a, b));
  return v.u;
}

// async global->LDS, 16B per lane. LDS dest = wave-uniform base + lane*16;
// global source is per-lane (pre-swizzled source pattern, m173/rule #21).
__device__ __forceinline__ void g2l16(const void* g, void* l) {
  __builtin_amdgcn_global_load_lds(
      (const __attribute__((address_space(1))) void*)g,
      (__attribute__((address_space(3))) void*)l, 16, 0, 0);
}

// d-slot permutation: slot(d) = (d&15)*4 + (d>>4). Applied consistently to
// Q/K d-dims (QK contraction invariant), att per-head d-dim + WoT k-rows
// (outproj contraction invariant). Exact.
//
// V key-slot permutation (attn swapped-QK in-register P): slot g (0..63)
// holds key tok(g) with bit map  tok5<-g5, tok4<-g2, tok3:2<-g4:3,
// tok1:0<-g1:0.  This makes the PV A-operand buildable from each lane's OWN
// exp'd QK outputs (no cross-lane exchange, no P LDS bounce).

// ---------------------------------------------------------------------------
// Merged prep (one launch): x->bf16, Wqkv->WT (bf16 transposed),
// Wo->WoT (bf16 transposed, k-rows sigma-permuted per head), RoPE table.
// ---------------------------------------------------------------------------
__global__ __launch_bounds__(256) void prep_kernel(
    const float* __restrict__ x,  const float* __restrict__ Wq,
    const float* __restrict__ Wk, const float* __restrict__ Wv,
    const float* __restrict__ Wo,
    short* __restrict__ xb, short* __restrict__ WT, short* __restrict__ WoT,
    float2* __restrict__ tbl) {
  __shared__ short Ts[64 * 72];
  const int bid = blockIdx.x, tid = threadIdx.x;

  if (bid < 2048) {                             // ---- x -> bf16
    const size_t i8 = ((size_t)bid * 256 + tid) * 8;
    const float4 a = *(const float4*)&x[i8];
    const float4 b = *(const float4*)&x[i8 + 4];
    uint4 p; p.x = pk2(a.x, a.y); p.y = pk2(a.z, a.w);
    p.z = pk2(b.x, b.y); p.w = pk2(b.z, b.w);
    *(uint4*)&xb[i8] = p;
  } else if (bid < 2688) {                      // ---- WT / WoT transpose
    const bool isW = bid < 2432;
    const int idx = isW ? (bid - 2048) : (bid - 2432);
    const int n0 = (idx >> 4) * 64, k0 = (idx & 15) * 64;
    const float* src; int ncols, c0; short* dst;
    if (isW) {
      dst = WT;
      if (n0 < 1024)      { src = Wq; ncols = 1024; c0 = n0; }
      else if (n0 < 1280) { src = Wk; ncols = 256;  c0 = n0 - 1024; }
      else                { src = Wv; ncols = 256;  c0 = n0 - 1280; }
    } else { dst = WoT; src = Wo; ncols = 1024; c0 = n0; }
    for (int i = tid; i < 1024; i += 256) {
      const int kr = i >> 4, c4 = (i & 15) << 2;
      // WoT k-rows permuted: slot(kr) = (kr&15)*4 + (kr>>4) (k0 is 64-aligned
      // = one head's range, so per-head sigma).
      const int kc = isW ? kr : ((kr & 15) * 4 + (kr >> 4));
      const float4 w = *(const float4*)&src[(size_t)(k0 + kr) * ncols + c0 + c4];
      Ts[(c4 + 0) * 72 + kc] = (short)f2bf(w.x);
      Ts[(c4 + 1) * 72 + kc] = (short)f2bf(w.y);
      Ts[(c4 + 2) * 72 + kc] = (short)f2bf(w.z);
      Ts[(c4 + 3) * 72 + kc] = (short)f2bf(w.w);
    }
    __syncthreads();
    for (int c = tid; c < 512; c += 256) {
      const int nr = c >> 3, c8 = (c & 7) * 8;
      *(bf16x8*)&dst[(size_t)(n0 + nr) * 1024 + k0 + c8] =
          *(const bf16x8*)&Ts[nr * 72 + c8];
    }
  } else {                                      // ---- RoPE table
    const int e = (bid - 2688) * 256 + tid;     // 65536 entries
    const int t = e >> 5, i2 = e & 31;
    const float freq = exp2f(-(float)(2 * i2) * (18.931568569324174f / 64.0f));
    float sn, cs; sincosf((float)t * freq, &sn, &cs);
    tbl[e] = make_float2(cs, sn);
  }
}

// ---------------------------------------------------------------------------
// Kernel 1: QKV projection, 128x64 tiles, T3-minimum 2-PHASE double-buffered
// K-loop: BK=64, 16 kt iters; per iter issue next tile's 6 g2l16, then
// COUNTED s_waitcnt vmcnt(6) (never 0 mid-loop) + raw s_barrier -> loads
// have a full compute phase to land. LDS 2x(16K+8K) = 48KB -> 3 blocks/CU.
// XOR block swizzle (8 blocks/row, blk ^= row&7; source-side pre-swizzle,
// rule #21). XCD-chunked grid 768. nt<16: Q (RoPE + QSCALE fold). 16..19: K
// (RoPE). 20..23: V (LDS-bounce transpose -> (b,kh,d,t), key slots permuted
// per attn's in-register-P map). [SESSION-BEST CONFIG, round 6 verbatim]
// ---------------------------------------------------------------------------
__global__ __launch_bounds__(256) void qkv_mfma_kernel(
    const short* __restrict__ xb, const short* __restrict__ WT,
    const float2* __restrict__ tbl,
    short* __restrict__ qo, short* __restrict__ ko, short* __restrict__ vt) {
  __shared__ short Xsh[2][128 * 64];
  __shared__ short Wth[2][64 * 64];
  const int tid = threadIdx.x;
  const int lane = tid & 63, w = tid >> 6;
  const int lm = lane & 15, quad = lane >> 4;
  // XCD-chunked decode: 768 = 8 XCDs x (4 m x 24 n)
  const int bid = blockIdx.x;
  const int xcd = bid & 7, slot = bid >> 3;     // slot 0..95
  const int m0 = (xcd * 4 + (slot & 3)) * 128;  // 0..3968
  const int n0 = (slot >> 2) * 64;              // 0..1472

  f32x4 acc[2][4];
  #pragma unroll
  for (int sm = 0; sm < 2; ++sm)
    #pragma unroll
    for (int ct = 0; ct < 4; ++ct) acc[sm][ct] = (f32x4){0.f, 0.f, 0.f, 0.f};

  // stage one BK=64 tile pair into buffer bsel (6 g2l16 per wave)
  auto stage = [&](int kt, int bsel) {
    #pragma unroll
    for (int u = 0; u < 4; ++u) {               // Xs: 128 rows, 8 rows/call
      const int r = u * 32 + w * 8 + (lane >> 3);
      const int sb = (lane & 7) ^ (r & 7);      // inverse-swizzled source blk
      g2l16(&xb[(size_t)(m0 + r) * 1024 + kt * 64 + sb * 8],
            &Xsh[bsel][(u * 32 + w * 8) * 64]);
    }
    #pragma unroll
    for (int u = 0; u < 2; ++u) {               // Wt: 64 rows
      const int r = u * 32 + w * 8 + (lane >> 3);
      const int sb = (lane & 7) ^ (r & 7);
      g2l16(&WT[(size_t)(n0 + r) * 1024 + kt * 64 + sb * 8],
            &Wth[bsel][(u * 32 + w * 8) * 64]);
    }
  };

  stage(0, 0);                                  // prologue
  for (int kt = 0; kt < 16; ++kt) {
    const int bsel = kt & 1;
    if (kt < 15) {
      stage(kt + 1, bsel ^ 1);                  // issue-early: flies w/ compute
      asm volatile("s_waitcnt vmcnt(6)" ::: "memory");  // cur tile landed
    } else {
      asm volatile("s_waitcnt vmcnt(0)" ::: "memory");
    }
    __builtin_amdgcn_s_barrier();               // all waves' cur data in LDS
    __builtin_amdgcn_sched_barrier(0);
    #pragma unroll
    for (int s2 = 0; s2 < 2; ++s2) {            // 2 k-steps of 32
      bf16x8 bfr[4];
      #pragma unroll
      for (int ct = 0; ct < 4; ++ct)
        bfr[ct] = *(const bf16x8*)&Wth[bsel][(ct * 16 + lm) * 64 +
                                            (((s2 * 4 + quad) ^ (lm & 7)) << 3)];
      #pragma unroll
      for (int sm = 0; sm < 2; ++sm) {
        const bf16x8 a = *(const bf16x8*)&Xsh[bsel][(w * 32 + sm * 16 + lm) * 64 +
                                            (((s2 * 4 + quad) ^ (lm & 7)) << 3)];
        #pragma unroll
        for (int ct = 0; ct < 4; ++ct)
          acc[sm][ct] =
              __builtin_amdgcn_mfma_f32_16x16x32_bf16(a, bfr[ct], acc[sm][ct], 0, 0, 0);
      }
    }
    __builtin_amdgcn_sched_barrier(0);
    __builtin_amdgcn_s_barrier();               // reads done before re-stage
  }

  if (n0 < 1280) {                              // ---- Q or K: RoPE + b64 store
    const bool isQ = n0 < 1024;
    short* outp = isQ ? qo : ko;
    const int base = isQ ? n0 : n0 - 1024;
    const int nh = isQ ? H_ : KH_;
    const int hh = base >> 6;                   // tile width 64 = one head
    const float post = isQ ? QSCALE : 1.0f;     // fold softmax scale into Q
    #pragma unroll
    for (int sm = 0; sm < 2; ++sm)
      #pragma unroll
      for (int r = 0; r < 4; ++r) {
        const int row = m0 + w * 32 + sm * 16 + quad * 4 + r;
        const int b = row >> 11, t = row & 2047;
        float v4[4];
        #pragma unroll
        for (int ct = 0; ct < 4; ++ct) {
          float val = acc[sm][ct][r];
          const float other = __shfl_xor(val, 1);
          const int ci = ct * 16 + lm;          // d within head
          const float2 cs = tbl[t * 32 + (ci >> 1)];
          val = ((ci & 1) == 0) ? (val * cs.x - other * cs.y)
                                : (val * cs.x + other * cs.y);
          v4[ct] = val * post;
        }
        // d ct*16+lm -> slot lm*4+ct: one b64 store of 4 consecutive slots
        uint2 st; st.x = pk2(v4[0], v4[1]); st.y = pk2(v4[2], v4[3]);
        *(uint2*)&outp[((size_t)(b * nh + hh) * T_ + t) * DH_ + lm * 4] = st;
      }
  } else {                                      // ---- V: LDS-bounce transpose
    short* XsF = &Xsh[0][0];                    // 16384 shorts scratch
    __syncthreads();                            // done with LDS as GEMM tiles
    #pragma unroll
    for (int sm = 0; sm < 2; ++sm)
      #pragma unroll
      for (int r = 0; r < 4; ++r)
        #pragma unroll
        for (int ct = 0; ct < 4; ++ct)
          XsF[(w * 32 + sm * 16 + quad * 4 + r) * 72 + ct * 16 + lm] =
              (short)f2bf(acc[sm][ct][r]);      // [t][d], stride 72 region
    __syncthreads();
    const int kh = (n0 - 1280) >> 6;
    const int b = m0 >> 11, t0 = m0 & 2047;
    short* vb = vt + (size_t)(b * KH_ + kh) * DH_ * T_;
    for (int c = tid; c < 1024; c += 256) {     // 64 d-rows x 16 chunks of 8 slots
      const int d = c >> 4, c8 = (c & 15) * 8;
      short tmp[8];
      #pragma unroll
      for (int j = 0; j < 8; ++j) {
        const int s = c8 + j, sg = s & 63;      // slot s -> token within group
        // tok bits: b5<-g5, b4<-g2, b3:2<-g4:3, b1:0<-g1:0 (in-reg P map)
        const int tok = (s & 64) | (sg & 35) | (((sg >> 2) & 1) << 4) |
                        (((sg >> 3) & 3) << 2);
        tmp[j] = XsF[tok * 72 + d];
      }
      *(bf16x8*)&vb[(size_t)d * T_ + t0 + c8] = *(bf16x8*)tmp;
    }
  }
}

// ---------------------------------------------------------------------------
// Kernel 2: causal flash attention, swapped-QK in-register-P structure
// [round-6 verbatim — the session-best total config]. One head/block, grid
// 1024 = 4/CU; PAIR-INTERLEAVE: QK0->QK1->SM0->PV0->SM1->PV1 (QK1 fills
// sacc0's MFMA latency; PV0 flies under SM1's VALU). qt interleave =
// constant 66 steps/CU; diag tiles skip masked MFMA blocks (wave-uniform);
// row-sum via MFMA ones-column; reg prefetch for K/V; s_setprio around MFMA
// clusters (T5). 64 arch VGPR, zero spill. Session lesson ledger: attn
// restructures 0-for-6 (grid r1, head-fusion r4, interleave r6, wave-split
// r8 [VGPR spill], 32x32 r11/r12 [spill, then chain-latency]) — any future
// change must fit 64 arch VGPR @ 4 blocks/CU and not deepen serial chains.
// ---------------------------------------------------------------------------
__global__ __launch_bounds__(256, 4) void attn_mfma_kernel(
    const short* __restrict__ q, const short* __restrict__ k,
    const short* __restrict__ vt, short* __restrict__ att) {
  __shared__ short Ks[128 * 72];
  __shared__ short Vts[64 * 136];               // [d][slot 0..127]

  const int bx = blockIdx.x;
  const int jj = bx & 255, c2 = bx >> 8;
  int qt = (c2 & 1) ? (jj >> 3) : (31 - (jj >> 3));   // heavy-first in chunk 0
  const int hb = (jj & 7) | (c2 << 3);
  const int h = hb >> 1, b = hb & 1;
  const int kh = h >> 2;                        // n_rep = 4
  const int tid = threadIdx.x;
  const int lane = tid & 63, w = tid >> 6;
  const int lm = lane & 15, quad = lane >> 4;
  const int q0 = qt * 64;

  const short* qb = q + (size_t)(b * H_ + h) * T_ * DH_;
  const short* kb = k + (size_t)(b * KH_ + kh) * T_ * DH_;
  const short* vb = vt + (size_t)(b * KH_ + kh) * DH_ * T_;

  bf16x8 ones;
  #pragma unroll
  for (int i = 0; i < 8; ++i) ones[i] = (short)0x3F80;  // bf16 1.0

  bf16x8 aq[2];                                 // kt-invariant Q fragments
  #pragma unroll
  for (int s = 0; s < 2; ++s)                   // direct global load (no LDS)
    aq[s] = *(const bf16x8*)&qb[(size_t)(q0 + w * 16 + lm) * 64 + s * 32 + quad * 8];

  bf16x8 pk[4], pv[4];
  #pragma unroll
  for (int u = 0; u < 4; ++u) {                 // preload r2=0 (128 keys)
    const int c = tid + u * 256;
    const int row = c >> 3, c8 = (c & 7) * 8;
    pk[u] = *(const bf16x8*)&kb[(size_t)row * 64 + c8];
    const int d = c >> 4, c16 = (c & 15) * 8;
    pv[u] = *(const bf16x8*)&vb[(size_t)d * T_ + c16];
  }

  f32x4 oacc[4], lacc;
  #pragma unroll
  for (int i = 0; i < 4; ++i) oacc[i] = (f32x4){0.f, 0.f, 0.f, 0.f};
  lacc = (f32x4){0.f, 0.f, 0.f, 0.f};

  // interleaved 128-key pair: QK0, QK1, SM0, PV0, SM1, PV1
  auto pairstep = [&](bool diag1) {
    f32x4 sacc0[4], sacc1[4];
    #pragma unroll
    for (int i = 0; i < 4; ++i) {
      sacc0[i] = (f32x4){0.f, 0.f, 0.f, 0.f};
      sacc1[i] = (f32x4){0.f, 0.f, 0.f, 0.f};
    }
    __builtin_amdgcn_s_setprio(1);
    #pragma unroll
    for (int s2 = 0; s2 < 2; ++s2)              // QK0 (never diagonal)
      #pragma unroll
      for (int ct = 0; ct < 4; ++ct) {
        const bf16x8 bb =
            *(const bf16x8*)&Ks[(ct * 16 + lm) * 72 + s2 * 32 + quad * 8];
        sacc0[ct] = __builtin_amdgcn_mfma_f32_16x16x32_bf16(bb, aq[s2], sacc0[ct], 0, 0, 0);
      }
    #pragma unroll
    for (int s2 = 0; s2 < 2; ++s2)              // QK1 (fills sacc0 latency)
      #pragma unroll
      for (int ct = 0; ct < 4; ++ct) {
        if (diag1 && ct > w) continue;          // fully-masked block, skip
        const bf16x8 bb =
            *(const bf16x8*)&Ks[(64 + ct * 16 + lm) * 72 + s2 * 32 + quad * 8];
        sacc1[ct] = __builtin_amdgcn_mfma_f32_16x16x32_bf16(bb, aq[s2], sacc1[ct], 0, 0, 0);
      }
    __builtin_amdgcn_s_setprio(0);
    // SM0: sacc0[ct][r] = P[key ct*16+quad*4+r][q w*16+lm]
    unsigned int pd0[4][2];
    #pragma unroll
    for (int ct = 0; ct < 4; ++ct) {
      float p[4];
      #pragma unroll
      for (int r = 0; r < 4; ++r) p[r] = EXP2F(sacc0[ct][r]);
      pd0[ct][0] = pk2(p[0], p[1]); pd0[ct][1] = pk2(p[2], p[3]);
    }
    __builtin_amdgcn_s_setprio(1);
    #pragma unroll
    for (int s2 = 0; s2 < 2; ++s2) {            // PV0
      union { bf16x8 v; unsigned int u[4]; } pa;
      pa.u[0] = pd0[2 * s2][0];     pa.u[1] = pd0[2 * s2][1];
      pa.u[2] = pd0[2 * s2 + 1][0]; pa.u[3] = pd0[2 * s2 + 1][1];
      lacc = __builtin_amdgcn_mfma_f32_16x16x32_bf16(pa.v, ones, lacc, 0, 0, 0);
      #pragma unroll
      for (int ct = 0; ct < 4; ++ct) {
        const bf16x8 vfr = *(const bf16x8*)&Vts[(ct * 16 + lm) * 136 +
                                                s2 * 32 + quad * 8];
        oacc[ct] = __builtin_amdgcn_mfma_f32_16x16x32_bf16(pa.v, vfr, oacc[ct], 0, 0, 0);
      }
    }
    __builtin_amdgcn_s_setprio(0);
    // SM1 (flies under PV0's MFMAs)
    unsigned int pd1[4][2];
    #pragma unroll
    for (int ct = 0; ct < 4; ++ct) {
      float p[4];
      #pragma unroll
      for (int r = 0; r < 4; ++r) {
        float e;
        if (diag1 && ct > w) e = 0.f;           // block fully above diagonal
        else {
          e = EXP2F(sacc1[ct][r]);
          if (diag1 && ct == w && (quad * 4 + r) > lm) e = 0.f;  // causal mask
        }
        p[r] = e;
      }
      pd1[ct][0] = pk2(p[0], p[1]); pd1[ct][1] = pk2(p[2], p[3]);
    }
    __builtin_amdgcn_s_setprio(1);
    #pragma unroll
    for (int s2 = 0; s2 < 2; ++s2) {            // PV1
      if (diag1 && 2 * s2 > w) continue;        // both ct' blocks masked
      union { bf16x8 v; unsigned int u[4]; } pa;
      pa.u[0] = pd1[2 * s2][0];     pa.u[1] = pd1[2 * s2][1];
      pa.u[2] = pd1[2 * s2 + 1][0]; pa.u[3] = pd1[2 * s2 + 1][1];
      lacc = __builtin_amdgcn_mfma_f32_16x16x32_bf16(pa.v, ones, lacc, 0, 0, 0);
      #pragma unroll
      for (int ct = 0; ct < 4; ++ct) {
        const bf16x8 vfr = *(const bf16x8*)&Vts[(ct * 16 + lm) * 136 +
                                                64 + s2 * 32 + quad * 8];
        oacc[ct] = __builtin_amdgcn_mfma_f32_16x16x32_bf16(pa.v, vfr, oacc[ct], 0, 0, 0);
      }
    }
    __builtin_amdgcn_s_setprio(0);
  };

  // peeled single 64-key diagonal step (j=0)
  auto dstep = [&]() {
    f32x4 sacc[4];
    #pragma unroll
    for (int i = 0; i < 4; ++i) sacc[i] = (f32x4){0.f, 0.f, 0.f, 0.f};
    __builtin_amdgcn_s_setprio(1);
    #pragma unroll
    for (int s2 = 0; s2 < 2; ++s2)
      #pragma unroll
      for (int ct = 0; ct < 4; ++ct) {
        if (ct > w) continue;
        const bf16x8 bb =
            *(const bf16x8*)&Ks[(ct * 16 + lm) * 72 + s2 * 32 + quad * 8];
        sacc[ct] = __builtin_amdgcn_mfma_f32_16x16x32_bf16(bb, aq[s2], sacc[ct], 0, 0, 0);
      }
    __builtin_amdgcn_s_setprio(0);
    unsigned int pd[4][2];
    #pragma unroll
    for (int ct = 0; ct < 4; ++ct) {
      float p[4];
      #pragma unroll
      for (int r = 0; r < 4; ++r) {
        float e;
        if (ct > w) e = 0.f;
        else {
          e = EXP2F(sacc[ct][r]);
          if (ct == w && (quad * 4 + r) > lm) e = 0.f;
        }
        p[r] = e;
      }
      pd[ct][0] = pk2(p[0], p[1]); pd[ct][1] = pk2(p[2], p[3]);
    }
    __builtin_amdgcn_s_setprio(1);
    #pragma unroll
    for (int s2 = 0; s2 < 2; ++s2) {
      if (2 * s2 > w) continue;
      union { bf16x8 v; unsigned int u[4]; } pa;
      pa.u[0] = pd[2 * s2][0];     pa.u[1] = pd[2 * s2][1];
      pa.u[2] = pd[2 * s2 + 1][0]; pa.u[3] = pd[2 * s2 + 1][1];
      lacc = __builtin_amdgcn_mfma_f32_16x16x32_bf16(pa.v, ones, lacc, 0, 0, 0);
      #pragma unroll
      for (int ct = 0; ct < 4; ++ct) {
        const bf16x8 vfr = *(const bf16x8*)&Vts[(ct * 16 + lm) * 136 +
                                                s2 * 32 + quad * 8];
        oacc[ct] = __builtin_amdgcn_mfma_f32_16x16x32_bf16(pa.v, vfr, oacc[ct], 0, 0, 0);
      }
    }
    __builtin_amdgcn_s_setprio(0);
  };

  auto stage = [&](int r2) {
    __syncthreads();                            // prior K/V LDS reads done
    #pragma unroll
    for (int u = 0; u < 4; ++u) {
      const int c = tid + u * 256;
      const int row = c >> 3, c8 = (c & 7) * 8;
      *(bf16x8*)&Ks[row * 72 + c8] = pk[u];
      const int d = c >> 4, c16 = (c & 15) * 8;
      *(bf16x8*)&Vts[d * 136 + c16] = pv[u];
    }
    __syncthreads();
    const int r2n = (r2 + 2 <= qt) ? (r2 + 2) : r2;   // prefetch next pair
    #pragma unroll
    for (int u = 0; u < 4; ++u) {
      const int c = tid + u * 256;
      const int row = c >> 3, c8 = (c & 7) * 8;
      pk[u] = *(const bf16x8*)&kb[(size_t)(r2n * 64 + row) * 64 + c8];
      const int d = c >> 4, c16 = (c & 15) * 8;
      pv[u] = *(const bf16x8*)&vb[(size_t)d * T_ + r2n * 64 + c16];
    }
  };

  int r2 = 0;
  for (; r2 + 1 <= qt; r2 += 2) {               // full pairs only
    stage(r2);
    pairstep(r2 + 1 == qt);                     // diag only on last pair's j=1
  }
  if (r2 == qt) {                               // peeled final step (even qt)
    stage(r2);
    dstep();
  }

  #pragma unroll
  for (int r = 0; r < 4; ++r) {
    const int qrow = q0 + w * 16 + quad * 4 + r;
    const float inv = 1.f / lacc[r];
    // d ct*16+lm -> slot lm*4+ct (WoT k-rows match): one b64 store
    uint2 st;
    st.x = pk2(oacc[0][r] * inv, oacc[1][r] * inv);
    st.y = pk2(oacc[2][r] * inv, oacc[3][r] * inv);
    *(uint2*)&att[((size_t)b * T_ + qrow) * 1024 + h * 64 + lm * 4] = st;
  }
}

// ---------------------------------------------------------------------------
// Kernel 3: output projection, 128x64 tiles, same 2-phase BK=64 double-
// buffered counted-vmcnt loop as kernel 1. Grid 512 XCD-chunked. bf16 in
// (slot-permuted k-dim, matched by WoT), fp32 out. [round-6 verbatim]
// ---------------------------------------------------------------------------
__global__ __launch_bounds__(256) void outproj_mfma_kernel(
    const short* __restrict__ att, const short* __restrict__ WoT,
    float* __restrict__ out) {
  __shared__ short Xsh[2][128 * 64];
  __shared__ short Wth[2][64 * 64];
  const int tid = threadIdx.x;
  const int lane = tid & 63, w = tid >> 6;
  const int lm = lane & 15, quad = lane >> 4;
  const int bid = blockIdx.x;
  const int xcd = bid & 7, slot = bid >> 3;     // slot 0..63
  const int m0 = (xcd * 4 + (slot & 3)) * 128;
  const int n0 = (slot >> 2) * 64;              // 0..960

  f32x4 acc[2][4];
  #pragma unroll
  for (int sm = 0; sm < 2; ++sm)
    #pragma unroll
    for (int ct = 0; ct < 4; ++ct) acc[sm][ct] = (f32x4){0.f, 0.f, 0.f, 0.f};

  auto stage = [&](int kt, int bsel) {
    #pragma unroll
    for (int u = 0; u < 4; ++u) {
      const int r = u * 32 + w * 8 + (lane >> 3);
      const int sb = (lane & 7) ^ (r & 7);
      g2l16(&att[(size_t)(m0 + r) * 1024 + kt * 64 + sb * 8],
            &Xsh[bsel][(u * 32 + w * 8) * 64]);
    }
    #pragma unroll
    for (int u = 0; u < 2; ++u) {
      const int r = u * 32 + w * 8 + (lane >> 3);
      const int sb = (lane & 7) ^ (r & 7);
      g2l16(&WoT[(size_t)(n0 + r) * 1024 + kt * 64 + sb * 8],
            &Wth[bsel][(u * 32 + w * 8) * 64]);
    }
  };

  stage(0, 0);
  for (int kt = 0; kt < 16; ++kt) {
    const int bsel = kt & 1;
    if (kt < 15) {
      stage(kt + 1, bsel ^ 1);
      asm volatile("s_waitcnt vmcnt(6)" ::: "memory");
    } else {
      asm volatile("s_waitcnt vmcnt(0)" ::: "memory");
    }
    __builtin_amdgcn_s_barrier();
    __builtin_amdgcn_sched_barrier(0);
    #pragma unroll
    for (int s2 = 0; s2 < 2; ++s2) {
      bf16x8 bfr[4];
      #pragma unroll
      for (int ct = 0; ct < 4; ++ct)
        bfr[ct] = *(const bf16x8*)&Wth[bsel][(ct * 16 + lm) * 64 +
                                            (((s2 * 4 + quad) ^ (lm & 7)) << 3)];
      #pragma unroll
      for (int sm = 0; sm < 2; ++sm) {
        const bf16x8 a = *(const bf16x8*)&Xsh[bsel][(w * 32 + sm * 16 + lm) * 64 +
                                            (((s2 * 4 + quad) ^ (lm & 7)) << 3)];
        #pragma unroll
        for (int ct = 0; ct < 4; ++ct)
          acc[sm][ct] =
              __builtin_amdgcn_mfma_f32_16x16x32_bf16(a, bfr[ct], acc[sm][ct], 0, 0, 0);
      }
    }
    __builtin_amdgcn_sched_barrier(0);
    __builtin_amdgcn_s_barrier();
  }

  #pragma unroll
  for (int sm = 0; sm < 2; ++sm)
    #pragma unroll
    for (int r = 0; r < 4; ++r) {
      const int row = m0 + w * 32 + sm * 16 + quad * 4 + r;
      #pragma unroll
      for (int ct = 0; ct < 4; ++ct)
        out[(size_t)row * 1024 + n0 + ct * 16 + lm] = acc[sm][ct][r];
    }
}

extern "C" void kernel_launch(void* const* d_in, const int* in_sizes, int n_in,
                              void* d_out, int out_size, void* d_ws, size_t ws_size,
                              hipStream_t stream) {
  const float* x  = (const float*)d_in[0];
  // d_in[1] = mask: fixed causal tril, handled analytically; never read.
  const float* Wq = (const float*)d_in[2];
  const float* Wk = (const float*)d_in[3];
  const float* Wv = (const float*)d_in[4];
  const float* Wo = (const float*)d_in[5];
  float* out = (float*)d_out;

  // ws carve (bf16 shorts unless noted): xb 8.4MB | WT 3.1MB | WoT 2.1MB |
  // q 8.4MB | k 2.1MB | vt 2.1MB | att 8.4MB | rope tbl 0.5MB  ~= 35.1MB
  short* xb   = (short*)d_ws;
  short* WT   = xb  + (size_t)4194304;          // 1536*1024
  short* WoT  = WT  + (size_t)1572864;          // 1024*1024 (k sigma-permuted)
  short* qb   = WoT + (size_t)1048576;          // 2*16*2048*64 (d sigma-permuted)
  short* kb   = qb  + (size_t)4194304;          // 2*4*2048*64 (d sigma-permuted)
  short* vtb  = kb  + (size_t)1048576;          // 2*4*64*2048 (transposed+permuted)
  short* attb = vtb + (size_t)1048576;          // 2*2048*1024 (d sigma-permuted)
  float2* tbl = (float2*)(attb + (size_t)4194304);  // 2048*32 float2

  prep_kernel<<<dim3(2944), dim3(256), 0, stream>>>(
      x, Wq, Wk, Wv, Wo, xb, WT, WoT, tbl);
  qkv_mfma_kernel<<<dim3(768), dim3(256), 0, stream>>>(xb, WT, tbl, qb, kb, vtb);
  attn_mfma_kernel<<<dim3(1024), dim3(256), 0, stream>>>(qb, kb, vtb, attb);
  outproj_mfma_kernel<<<dim3(512), dim3(256), 0, stream>>>(attb, WoT, out);
}